// Round 3
// baseline (612.836 us; speedup 1.0000x reference)
//
#include <hip/hip_runtime.h>

// ---------------------------------------------------------------------------
// O3onO2 tensor product, LS=[0,1,2,3], MULS=64 each, N=65536, DIM=1024.
// Formulation: out = x @ M^T where M is block-diagonal after grouping
// channels by m:  m=0: 256x256, m=1: 384x384, m=2: 256x256, m=3: 128x128.
// M_m[(ob_rel,so,o),(ib_rel,si,i)] = C[so][si] * W_p[o,i],  p = ob*4+ib,
//   C = [[hp, hn], [-hn, hp]]  (m>=1),  C = [[hzero]] (m=0).
//
// R1: LDS-staged coalesced epilogue (write amp 4.4x -> 1.0x). 204 us.
// R2: 32 rows/WG regressed (274 us): B-amortization halved. Reverted.
// R3: 64 rows/WG, 8 waves x 512 thr (__launch_bounds__(512,2) -> 256
//     regs/thr: acc[8][4]=128 AGPR + up to 128 VGPR). T14 async-stage:
//     issue global loads of block l+1 into registers BEFORE compute(l),
//     convert+LDS-write after; load latency hides under MFMA phase.
// ---------------------------------------------------------------------------

typedef __attribute__((ext_vector_type(8))) short bhalf8_t;   // 8 x bf16 bits
typedef __attribute__((ext_vector_type(4))) float f32x4_t;

#define NROWS 65536
#define DIMV  1024
#define NT    512          // threads per WG (8 waves)
#define RPW   64           // rows per WG

// M_m element offsets in workspace (bf16 elements)
#define M0_OFF 0
#define M1_OFF 65536
#define M2_OFF 212992
#define M3_OFF 278528
#define M_TOTAL 294912

// Epilogue LDS tile: 16 rows x 1024 cols fp32, padded row stride.
#define OP 1028

__device__ __forceinline__ short f2bf(float f) {
    unsigned u = __builtin_bit_cast(unsigned, f);
    u = (u + 0x7FFFu + ((u >> 16) & 1u)) >> 16;   // round-to-nearest-even
    return (short)u;
}

// ---------------------------------------------------------------------------
// Kernel 1: build block-diagonal group matrices M_m (bf16) into workspace.
// ---------------------------------------------------------------------------
__global__ __launch_bounds__(256) void build_M(const float* __restrict__ w,
                                               const float* __restrict__ hz,
                                               const float* __restrict__ hp,
                                               const float* __restrict__ hn,
                                               short* __restrict__ M) {
    int idx = blockIdx.x * 256 + threadIdx.x;
    if (idx >= M_TOTAL) return;

    int m, A, B;
    if (idx < M1_OFF)      { m = 0; int lo = idx;            A = lo / 256u; B = lo - A * 256; }
    else if (idx < M2_OFF) { m = 1; int lo = idx - M1_OFF;   A = lo / 384u; B = lo - A * 384; }
    else if (idx < M3_OFF) { m = 2; int lo = idx - M2_OFF;   A = lo / 256u; B = lo - A * 256; }
    else                   { m = 3; int lo = idx - M3_OFF;   A = lo / 128u; B = lo - A * 128; }

    int ob, so, o, ib, si, i;
    if (m == 0) { ob = A >> 6;       so = 0;            o = A & 63;
                  ib = B >> 6;       si = 0;            i = B & 63; }
    else        { ob = (A >> 7) + m; so = (A >> 6) & 1; o = A & 63;
                  ib = (B >> 7) + m; si = (B >> 6) & 1; i = B & 63; }

    int p = ob * 4 + ib;
    float wv = w[p * 4096 + o * 64 + i];
    float coef;
    if (m == 0) {
        coef = hz[p];
    } else {
        float hpv = hp[p * 3 + (m - 1)];
        float hnv = hn[p * 3 + (m - 1)];
        coef = (so == 0) ? ((si == 0) ? hpv : hnv)
                         : ((si == 0) ? -hnv : hpv);
    }
    M[idx] = f2bf(wv * coef);
}

// ---------------------------------------------------------------------------
// Stage split (T14): load_block issues the global float4 loads into regs;
// write_block (later) converts and scatters to LDS channel-major layout
// [row][ji*72 + i].
// ---------------------------------------------------------------------------
template<int L>
__device__ __forceinline__ void load_block(const float* __restrict__ x, int rowbase,
                                           int tid, float4* __restrict__ v) {
    constexpr int nch = 2 * L + 1;
    constexpr int d4  = 16 * nch;       // float4-chunks per row in this block
    constexpr int bo  = 64 * L * L;     // block col offset in x
#pragma unroll
    for (int e = 0; e < 2 * nch; ++e) {
        int id  = e * NT + tid;
        int row = id / d4;
        int cc  = id - row * d4;
        v[e] = *(const float4*)(x + (size_t)(rowbase + row) * DIMV + bo + cc * 4);
    }
}

template<int L>
__device__ __forceinline__ void write_block(const float4* __restrict__ v,
                                            short* __restrict__ xb, int tid) {
    constexpr int nch = 2 * L + 1;
    constexpr int d4  = 16 * nch;
    constexpr int RS  = nch * 72;       // LDS row stride (elements)
#pragma unroll
    for (int e = 0; e < 2 * nch; ++e) {
        int id  = e * NT + tid;
        int row = id / d4;
        int cc  = id - row * d4;
        int col = cc * 4;
        short* dst = &xb[row * RS];
        const float4 w = v[e];
        { int ci = col;     int i = ci / nch; int ji = ci - i * nch; dst[ji * 72 + i] = f2bf(w.x); }
        { int ci = col + 1; int i = ci / nch; int ji = ci - i * nch; dst[ji * 72 + i] = f2bf(w.y); }
        { int ci = col + 2; int i = ci / nch; int ji = ci - i * nch; dst[ji * 72 + i] = f2bf(w.z); }
        { int ci = col + 3; int i = ci / nch; int ji = ci - i * nch; dst[ji * 72 + i] = f2bf(w.w); }
    }
}

// ---------------------------------------------------------------------------
// Compute one l-block's contribution for this wave's m-group.
// 8 col-tiles x 4 row-tiles; B from global (L2-resident M).
// ---------------------------------------------------------------------------
template<int L>
__device__ __forceinline__ void compute_block(const short* __restrict__ xb,
                                              const short* __restrict__ Mg,
                                              int m, int Wm, int cb, int lr, int q,
                                              f32x4_t (&acc)[8][4]) {
    if (m > L) return;
    constexpr int nch = 2 * L + 1;
    constexpr int RS  = nch * 72;
    const int nsi = (m == 0) ? 1 : 2;
    for (int si = 0; si < nsi; ++si) {
        const int ji    = L + ((si == 0) ? m : -m);
        const int kbase = (m == 0) ? (L << 6) : (((L - m) << 7) + (si << 6));
#pragma unroll
        for (int kk = 0; kk < 2; ++kk) {
            bhalf8_t a[4];
            const int eo = ji * 72 + kk * 32 + q * 8;
#pragma unroll
            for (int r = 0; r < 4; ++r)
                a[r] = *(const bhalf8_t*)&xb[(r * 16 + lr) * RS + eo];
            const int ko = kbase + kk * 32 + q * 8;
#pragma unroll
            for (int c = 0; c < 8; ++c) {
                const bhalf8_t b = *(const bhalf8_t*)&Mg[(cb + c * 16 + lr) * Wm + ko];
#pragma unroll
                for (int r = 0; r < 4; ++r)
                    acc[c][r] = __builtin_amdgcn_mfma_f32_16x16x32_bf16(
                        a[r], b, acc[c][r], 0, 0, 0);
            }
        }
    }
}

// ---------------------------------------------------------------------------
// Kernel 2: main. One WG = 64 rows x all 1024 out cols. 512 threads (8
// waves). Waves 0-1: m=0 (2x128 cols), 2-4: m=1 (3x128), 5-6: m=2 (2x128),
// 7: m=3 (128). Each wave: 8 col-tiles x 4 row-tiles of 16x16 MFMA.
// ---------------------------------------------------------------------------
__global__ __launch_bounds__(NT, 2) void tp_main(const float* __restrict__ x,
                                                 const short* __restrict__ Mall,
                                                 float* __restrict__ out) {
    // Shared pool, reused:
    //  phase A (compute): single x-tile buffer, max l=3: 16128 sh = 32256 B.
    //  phase B (epilogue): 16 x OP fp32 output staging = 65792 B.
    __shared__ __align__(16) char smem[16 * OP * 4];
    short* __restrict__ xbuf = (short*)smem;
    float* __restrict__ obuf = (float*)smem;

    const int tid  = threadIdx.x;
    const int lane = tid & 63;
    const int lr   = lane & 15;       // MFMA row/col lane index
    const int q    = lane >> 4;       // quad
    const int wv   = tid >> 6;        // wave id 0..7
    const int rowbase = blockIdx.x * RPW;

    int m, cb;
    if      (wv < 2) { m = 0; cb = wv << 7; }
    else if (wv < 5) { m = 1; cb = (wv - 2) << 7; }
    else if (wv < 7) { m = 2; cb = (wv - 5) << 7; }
    else             { m = 3; cb = 0; }
    const int Wm   = (m == 1) ? 384 : ((m == 3) ? 128 : 256);
    const int Moff = (m == 0) ? M0_OFF : (m == 1) ? M1_OFF : (m == 2) ? M2_OFF : M3_OFF;
    const short* __restrict__ Mg = Mall + Moff;

    f32x4_t acc[8][4];   // [col-tile][row-tile] -> 128 AGPRs
#pragma unroll
    for (int c = 0; c < 8; ++c)
#pragma unroll
        for (int r = 0; r < 4; ++r)
            acc[c][r] = (f32x4_t){0.f, 0.f, 0.f, 0.f};

    // ---- T14 pipeline: loads of block l+1 issued before compute(l);
    //      convert+LDS-write after the post-compute barrier.
    float4 v0[2], v1[6], v2[10], v3[14];

    load_block<0>(x, rowbase, tid, v0);
    write_block<0>(v0, xbuf, tid);
    __syncthreads();

    load_block<1>(x, rowbase, tid, v1);                 // in flight over compute<0>
    compute_block<0>(xbuf, Mg, m, Wm, cb, lr, q, acc);
    __syncthreads();
    write_block<1>(v1, xbuf, tid);
    __syncthreads();

    load_block<2>(x, rowbase, tid, v2);                 // in flight over compute<1>
    compute_block<1>(xbuf, Mg, m, Wm, cb, lr, q, acc);
    __syncthreads();
    write_block<2>(v2, xbuf, tid);
    __syncthreads();

    load_block<3>(x, rowbase, tid, v3);                 // in flight over compute<2>
    compute_block<2>(xbuf, Mg, m, Wm, cb, lr, q, acc);
    __syncthreads();
    write_block<3>(v3, xbuf, tid);
    __syncthreads();

    compute_block<3>(xbuf, Mg, m, Wm, cb, lr, q, acc);

    // ---- epilogue: un-permute columns via LDS, drain with coalesced float4.
    // C/D layout: col = lane&15, row = (lane>>4)*4 + reg   [m89-verified]
    int origc[8];
#pragma unroll
    for (int c = 0; c < 8; ++c) {
        const int P = cb + c * 16 + lr;
        int ob, o, jo;
        if (m == 0) { ob = P >> 6;       o = P & 63; jo = ob; }
        else        { ob = (P >> 7) + m; o = P & 63;
                      jo = ob + ((((P >> 6) & 1) == 0) ? m : -m); }
        origc[c] = 64 * ob * ob + o * (2 * ob + 1) + jo;
    }

#pragma unroll
    for (int r2 = 0; r2 < 4; ++r2) {
        __syncthreads();   // r2=0: xbuf readers done; else: prev drain done
        // scatter this 16-row slice into LDS (4B LDS writes, odd strides)
#pragma unroll
        for (int c = 0; c < 8; ++c) {
#pragma unroll
            for (int g = 0; g < 4; ++g)
                obuf[(q * 4 + g) * OP + origc[c]] = acc[c][r2][g];
        }
        __syncthreads();
        // drain: 16 rows x 1024 cols = 4096 float4, 8 per thread, coalesced
#pragma unroll
        for (int it = 0; it < 8; ++it) {
            const int j   = it * NT + tid;
            const int row = j >> 8;
            const int c4  = (j & 255) << 2;
            const float4 v = *(const float4*)&obuf[row * OP + c4];
            *(float4*)&out[(size_t)(rowbase + r2 * 16 + row) * DIMV + c4] = v;
        }
    }
}

// ---------------------------------------------------------------------------
extern "C" void kernel_launch(void* const* d_in, const int* in_sizes, int n_in,
                              void* d_out, int out_size, void* d_ws, size_t ws_size,
                              hipStream_t stream) {
    const float* x   = (const float*)d_in[0];
    const float* wts = (const float*)d_in[1];
    const float* hz  = (const float*)d_in[2];
    const float* hp  = (const float*)d_in[3];
    const float* hn  = (const float*)d_in[4];
    float* out = (float*)d_out;
    short* M   = (short*)d_ws;   // needs 294912 * 2 = 589824 bytes

    build_M<<<dim3(M_TOTAL / 256), dim3(256), 0, stream>>>(wts, hz, hp, hn, M);
    tp_main<<<dim3(NROWS / RPW), dim3(NT), 0, stream>>>(x, M, out);
}

// Round 4
// 528.725 us; speedup vs baseline: 1.1591x; 1.1591x over previous
//
#include <hip/hip_runtime.h>

// ---------------------------------------------------------------------------
// O3onO2 tensor product, LS=[0,1,2,3], MULS=64 each, N=65536, DIM=1024.
// Formulation: out = x @ M^T where M is block-diagonal after grouping
// channels by m:  m=0: 256x256, m=1: 384x384, m=2: 256x256, m=3: 128x128.
// M_m[(ob_rel,so,o),(ib_rel,si,i)] = C[so][si] * W_p[o,i],  p = ob*4+ib,
//   C = [[hp, hn], [-hn, hp]]  (m>=1),  C = [[hzero]] (m=0).
//
// R1: LDS-staged coalesced epilogue (write amp 4.4x -> 1.0x). 204 us.
// R2: 32 rows/WG regressed (274 us): B-amortization halved. Reverted.
// R3: 8-wave/256-reg + reg-held prefetch regressed (306 us): spills
//     (WRITE +257MB scratch), 8 waves/CU. Reverted to R1 shape.
// R4: within R1 shape (1024 thr, 16 waves, acc[4][4]): stage ALL four
//     l-blocks into one 144KB LDS x-buffer up front (deep load burst),
//     ONE barrier, then all compute blocks contiguous, barrier-free.
//     Main-loop barriers 8 -> 1.
// ---------------------------------------------------------------------------

typedef __attribute__((ext_vector_type(8))) short bhalf8_t;   // 8 x bf16 bits
typedef __attribute__((ext_vector_type(4))) float f32x4_t;

#define NROWS 65536
#define DIMV  1024
#define NT    1024         // threads per WG (16 waves)
#define RPW   64           // rows per WG

// M_m element offsets in workspace (bf16 elements)
#define M0_OFF 0
#define M1_OFF 65536
#define M2_OFF 212992
#define M3_OFF 278528
#define M_TOTAL 294912

// Epilogue LDS tile: 16 rows x 1024 cols fp32, padded row stride.
#define OP 1028

// xbuf block offsets (shorts): block l, row stride RS_l = (2l+1)*72.
// sizes (shorts): 4608, 13824, 23040, 32256 -> total 73728 sh = 147456 B.
__device__ __forceinline__ constexpr int xoff(int L) {
    return (L == 0) ? 0 : (L == 1) ? 4608 : (L == 2) ? 18432 : 41472;
}

__device__ __forceinline__ short f2bf(float f) {
    unsigned u = __builtin_bit_cast(unsigned, f);
    u = (u + 0x7FFFu + ((u >> 16) & 1u)) >> 16;   // round-to-nearest-even
    return (short)u;
}

// ---------------------------------------------------------------------------
// Kernel 1: build block-diagonal group matrices M_m (bf16) into workspace.
// ---------------------------------------------------------------------------
__global__ __launch_bounds__(256) void build_M(const float* __restrict__ w,
                                               const float* __restrict__ hz,
                                               const float* __restrict__ hp,
                                               const float* __restrict__ hn,
                                               short* __restrict__ M) {
    int idx = blockIdx.x * 256 + threadIdx.x;
    if (idx >= M_TOTAL) return;

    int m, A, B;
    if (idx < M1_OFF)      { m = 0; int lo = idx;            A = lo / 256u; B = lo - A * 256; }
    else if (idx < M2_OFF) { m = 1; int lo = idx - M1_OFF;   A = lo / 384u; B = lo - A * 384; }
    else if (idx < M3_OFF) { m = 2; int lo = idx - M2_OFF;   A = lo / 256u; B = lo - A * 256; }
    else                   { m = 3; int lo = idx - M3_OFF;   A = lo / 128u; B = lo - A * 128; }

    int ob, so, o, ib, si, i;
    if (m == 0) { ob = A >> 6;       so = 0;            o = A & 63;
                  ib = B >> 6;       si = 0;            i = B & 63; }
    else        { ob = (A >> 7) + m; so = (A >> 6) & 1; o = A & 63;
                  ib = (B >> 7) + m; si = (B >> 6) & 1; i = B & 63; }

    int p = ob * 4 + ib;
    float wv = w[p * 4096 + o * 64 + i];
    float coef;
    if (m == 0) {
        coef = hz[p];
    } else {
        float hpv = hp[p * 3 + (m - 1)];
        float hnv = hn[p * 3 + (m - 1)];
        coef = (so == 0) ? ((si == 0) ? hpv : hnv)
                         : ((si == 0) ? -hnv : hpv);
    }
    M[idx] = f2bf(wv * coef);
}

// ---------------------------------------------------------------------------
// Stage one l-block of x (64 rows) into LDS, channel-major [row][ji*72 + i].
// ---------------------------------------------------------------------------
template<int L>
__device__ __forceinline__ void stage_block(const float* __restrict__ x, int rowbase,
                                            short* __restrict__ xb, int tid) {
    constexpr int nch = 2 * L + 1;
    constexpr int d4  = 16 * nch;       // float4-chunks per row in this block
    constexpr int RS  = nch * 72;       // LDS row stride (elements)
    constexpr int bo  = 64 * L * L;     // block col offset in x
#pragma unroll
    for (int e = 0; e < nch; ++e) {     // exactly nch full passes of NT thr
        int id  = e * NT + tid;
        int row = id / d4;
        int cc  = id - row * d4;
        int col = cc * 4;
        const float4 v = *(const float4*)(x + (size_t)(rowbase + row) * DIMV + bo + col);
        short* dst = &xb[row * RS];
        { int ci = col;     int i = ci / nch; int ji = ci - i * nch; dst[ji * 72 + i] = f2bf(v.x); }
        { int ci = col + 1; int i = ci / nch; int ji = ci - i * nch; dst[ji * 72 + i] = f2bf(v.y); }
        { int ci = col + 2; int i = ci / nch; int ji = ci - i * nch; dst[ji * 72 + i] = f2bf(v.z); }
        { int ci = col + 3; int i = ci / nch; int ji = ci - i * nch; dst[ji * 72 + i] = f2bf(v.w); }
    }
}

// ---------------------------------------------------------------------------
// Compute one l-block's contribution for this wave's m-group.
// 4 col-tiles x 4 row-tiles; B from global (L2-resident M).
// ---------------------------------------------------------------------------
template<int L>
__device__ __forceinline__ void compute_block(const short* __restrict__ xb,
                                              const short* __restrict__ Mg,
                                              int m, int Wm, int cb, int lr, int q,
                                              f32x4_t (&acc)[4][4]) {
    if (m > L) return;
    constexpr int nch = 2 * L + 1;
    constexpr int RS  = nch * 72;
    const int nsi = (m == 0) ? 1 : 2;
    for (int si = 0; si < nsi; ++si) {
        const int ji    = L + ((si == 0) ? m : -m);
        const int kbase = (m == 0) ? (L << 6) : (((L - m) << 7) + (si << 6));
#pragma unroll
        for (int kk = 0; kk < 2; ++kk) {
            bhalf8_t a[4];
            const int eo = ji * 72 + kk * 32 + q * 8;
#pragma unroll
            for (int r = 0; r < 4; ++r)
                a[r] = *(const bhalf8_t*)&xb[(r * 16 + lr) * RS + eo];
            const int ko = kbase + kk * 32 + q * 8;
#pragma unroll
            for (int c = 0; c < 4; ++c) {
                const bhalf8_t b = *(const bhalf8_t*)&Mg[(cb + c * 16 + lr) * Wm + ko];
#pragma unroll
                for (int r = 0; r < 4; ++r)
                    acc[c][r] = __builtin_amdgcn_mfma_f32_16x16x32_bf16(
                        a[r], b, acc[c][r], 0, 0, 0);
            }
        }
    }
}

// ---------------------------------------------------------------------------
// Kernel 2: main. One WG = 64 rows x all 1024 out cols. 1024 threads (16
// waves). Waves 0-3: m=0 (256 cols), 4-9: m=1 (384), 10-13: m=2 (256),
// 14-15: m=3 (128). Each wave: 4 col-tiles x 4 row-tiles of 16x16 MFMA.
// ---------------------------------------------------------------------------
__global__ __launch_bounds__(NT) void tp_main(const float* __restrict__ x,
                                              const short* __restrict__ Mall,
                                              float* __restrict__ out) {
    // Shared pool:
    //  phase A (compute): all four x-blocks, 73728 sh = 147456 B.
    //  phase B (epilogue): 16 x OP fp32 output staging = 65792 B (aliases).
    __shared__ __align__(16) char smem[147456];
    short* __restrict__ xbuf = (short*)smem;
    float* __restrict__ obuf = (float*)smem;

    const int tid  = threadIdx.x;
    const int lane = tid & 63;
    const int lr   = lane & 15;       // MFMA row/col lane index
    const int q    = lane >> 4;       // quad
    const int wv   = tid >> 6;        // wave id 0..15
    const int rowbase = blockIdx.x * RPW;

    int m, cb;
    if (wv < 4)       { m = 0; cb = wv << 6; }
    else if (wv < 10) { m = 1; cb = (wv - 4) << 6; }
    else if (wv < 14) { m = 2; cb = (wv - 10) << 6; }
    else              { m = 3; cb = (wv - 14) << 6; }
    const int Wm   = (m == 1) ? 384 : ((m == 3) ? 128 : 256);
    const int Moff = (m == 0) ? M0_OFF : (m == 1) ? M1_OFF : (m == 2) ? M2_OFF : M3_OFF;
    const short* __restrict__ Mg = Mall + Moff;

    f32x4_t acc[4][4];   // [col-tile][row-tile] -> 64 AGPRs
#pragma unroll
    for (int c = 0; c < 4; ++c)
#pragma unroll
        for (int r = 0; r < 4; ++r)
            acc[c][r] = (f32x4_t){0.f, 0.f, 0.f, 0.f};

    // ---- stage all four blocks (deep independent load burst), ONE barrier
    stage_block<0>(x, rowbase, xbuf + xoff(0), tid);
    stage_block<1>(x, rowbase, xbuf + xoff(1), tid);
    stage_block<2>(x, rowbase, xbuf + xoff(2), tid);
    stage_block<3>(x, rowbase, xbuf + xoff(3), tid);
    __syncthreads();

    // ---- compute all blocks back-to-back, barrier-free
    compute_block<0>(xbuf + xoff(0), Mg, m, Wm, cb, lr, q, acc);
    compute_block<1>(xbuf + xoff(1), Mg, m, Wm, cb, lr, q, acc);
    compute_block<2>(xbuf + xoff(2), Mg, m, Wm, cb, lr, q, acc);
    compute_block<3>(xbuf + xoff(3), Mg, m, Wm, cb, lr, q, acc);

    // ---- epilogue: un-permute columns via LDS, drain with coalesced float4.
    // C/D layout: col = lane&15, row = (lane>>4)*4 + reg   [m89-verified]
    int origc[4];
#pragma unroll
    for (int c = 0; c < 4; ++c) {
        const int P = cb + c * 16 + lr;
        int ob, o, jo;
        if (m == 0) { ob = P >> 6;       o = P & 63; jo = ob; }
        else        { ob = (P >> 7) + m; o = P & 63;
                      jo = ob + ((((P >> 6) & 1) == 0) ? m : -m); }
        origc[c] = 64 * ob * ob + o * (2 * ob + 1) + jo;
    }

#pragma unroll
    for (int r = 0; r < 4; ++r) {
        __syncthreads();   // r=0: compute's xbuf reads done; else: drain done
        // scatter this 16-row slice into LDS (4B LDS writes, odd strides)
#pragma unroll
        for (int c = 0; c < 4; ++c) {
#pragma unroll
            for (int g = 0; g < 4; ++g)
                obuf[(q * 4 + g) * OP + origc[c]] = acc[c][r][g];
        }
        __syncthreads();
        // drain: 16 rows x 1024 cols = 4096 float4, 4 per thread, coalesced
#pragma unroll
        for (int it = 0; it < 4; ++it) {
            const int j   = it * NT + tid;
            const int row = j >> 8;
            const int c4  = (j & 255) << 2;
            const float4 v = *(const float4*)&obuf[row * OP + c4];
            *(float4*)&out[(size_t)(rowbase + r * 16 + row) * DIMV + c4] = v;
        }
    }
}

// ---------------------------------------------------------------------------
extern "C" void kernel_launch(void* const* d_in, const int* in_sizes, int n_in,
                              void* d_out, int out_size, void* d_ws, size_t ws_size,
                              hipStream_t stream) {
    const float* x   = (const float*)d_in[0];
    const float* wts = (const float*)d_in[1];
    const float* hz  = (const float*)d_in[2];
    const float* hp  = (const float*)d_in[3];
    const float* hn  = (const float*)d_in[4];
    float* out = (float*)d_out;
    short* M   = (short*)d_ws;   // needs 294912 * 2 = 589824 bytes

    build_M<<<dim3(M_TOTAL / 256), dim3(256), 0, stream>>>(wts, hz, hp, hn, M);
    tp_main<<<dim3(NROWS / RPW), dim3(NT), 0, stream>>>(x, M, out);
}